// Round 4
// baseline (1063.035 us; speedup 1.0000x reference)
//
#include <hip/hip_runtime.h>

#define N_NODES 50000
#define N_EDGES 800000
#define IN_CH 128
#define HID_CH 96
#define OUT_CH 40
#define EPS 1e-5f

// ---------------- bf16 pack/unpack ----------------

__device__ __forceinline__ unsigned packbf(float a, float b) {
    unsigned ua = __float_as_uint(a), ub = __float_as_uint(b);
    ua += 0x7fffu + ((ua >> 16) & 1u);           // RTNE
    ub += 0x7fffu + ((ub >> 16) & 1u);
    return (ua >> 16) | (ub & 0xffff0000u);
}

__device__ __forceinline__ float4 unpack4(uint2 v) {
    return make_float4(__uint_as_float(v.x << 16), __uint_as_float(v.x & 0xffff0000u),
                       __uint_as_float(v.y << 16), __uint_as_float(v.y & 0xffff0000u));
}

// ---------------- CSR build ----------------

__global__ void count_kernel(const int* __restrict__ ei, int* __restrict__ cnt) {
    int e = blockIdx.x * blockDim.x + threadIdx.x;
    if (e >= N_EDGES) return;
    int s = ei[e], d = ei[N_EDGES + e];
    if (s != d) atomicAdd(&cnt[d], 1);
}

__global__ void norm_kernel(const int* __restrict__ cnt, float* __restrict__ dinv,
                            float* __restrict__ selfw) {
    int n = blockIdx.x * blockDim.x + threadIdx.x;
    if (n >= N_NODES) return;
    float deg = (float)(cnt[n] + 1);
    dinv[n]  = rsqrtf(deg);
    selfw[n] = 1.0f / deg;
}

__global__ void scan_kernel(const int* __restrict__ cnt, int* __restrict__ row_start) {
    __shared__ int partial[256];
    const int T = 256;
    int tid = threadIdx.x;
    int seg = (N_NODES + T - 1) / T;
    int s0 = tid * seg;
    int s1 = s0 + seg; if (s1 > N_NODES) s1 = N_NODES;
    int sum = 0;
    for (int i = s0; i < s1; i++) sum += cnt[i];
    partial[tid] = sum;
    __syncthreads();
    if (tid == 0) {
        int acc = 0;
        for (int i = 0; i < T; i++) { int v = partial[i]; partial[i] = acc; acc += v; }
    }
    __syncthreads();
    int acc = partial[tid];
    for (int i = s0; i < s1; i++) { row_start[i] = acc; acc += cnt[i]; }
    if (tid == T - 1) row_start[N_NODES] = acc;
}

__global__ void fill_kernel(const int* __restrict__ ei, const int* __restrict__ row_start,
                            int* __restrict__ fillp, const float* __restrict__ dinv,
                            int2* __restrict__ cw) {
    int e = blockIdx.x * blockDim.x + threadIdx.x;
    if (e >= N_EDGES) return;
    int s = ei[e], d = ei[N_EDGES + e];
    if (s == d) return;
    int p = atomicAdd(&fillp[d], 1);
    int idx = row_start[d] + p;
    cw[idx] = make_int2(s, __float_as_int(dinv[s] * dinv[d]));
}

__global__ void bn_fin(const float* __restrict__ sums, const float* __restrict__ sq,
                       float* __restrict__ mu, float* __restrict__ inv) {
    int c = threadIdx.x;
    if (c >= HID_CH) return;
    float m = sums[c] * (1.0f / N_NODES);
    float v = sq[c] * (1.0f / N_NODES) - m * m;
    mu[c] = m; inv[c] = rsqrtf(v + EPS);
}

// ---------------- GEMM v3: wave-uniform W (scalar loads), X per-lane ----------------
// wave = 64 nodes x CPT output channels. No LDS, no barriers.
// NORMX: X normalized (BN+ReLU) on load via mu/inv. BLEND: out = (1-b)*xn + b*acc.
// PACKOUT: write packed bf16 to outb, else fp32 to outf. H0OUT: also write packed xn.
// STATS: butterfly-reduce raw acc -> global atomics (gemm0 only).

template <int K, int C, int CPT, bool BLEND, bool NORMX, bool STATS, bool PACKOUT, bool H0OUT>
__global__ __launch_bounds__(256) void gemm3(
    const float* __restrict__ X, const float* __restrict__ W,
    float* __restrict__ outf, unsigned* __restrict__ outb, unsigned* __restrict__ h0n,
    const float* __restrict__ muin, const float* __restrict__ invin,
    float* __restrict__ osum, float* __restrict__ osq, float beta) {
    constexpr int K4 = K / 4;
    constexpr int PARTS = C / CPT;
    constexpr int NB = (N_NODES + 63) / 64;
    constexpr int NITEMS = NB * PARTS;
    const int lane = threadIdx.x & 63;
    const int nwaves = (gridDim.x * blockDim.x) >> 6;
    const float4* X4 = (const float4*)X;
    const float4* W4 = (const float4*)W;
    int gw0 = __builtin_amdgcn_readfirstlane((blockIdx.x * blockDim.x + threadIdx.x) >> 6);
    for (int item = gw0; item < NITEMS; item += nwaves) {
        const int part = item / NB;                 // uniform
        const int nb   = item - part * NB;          // uniform
        const int obase = part * CPT;               // uniform
        const int n = nb * 64 + lane;
        const bool valid = n < N_NODES;
        const int nc = valid ? n : N_NODES - 1;
        float acc[CPT];
#pragma unroll
        for (int o = 0; o < CPT; o++) acc[o] = 0.0f;
        for (int k4 = 0; k4 < K4; ++k4) {
            float4 xv = X4[(size_t)nc * K4 + k4];
            if (!valid) xv = make_float4(0.f, 0.f, 0.f, 0.f);
            if (NORMX) {
                float4 m  = *(const float4*)&muin[k4 * 4];
                float4 iv = *(const float4*)&invin[k4 * 4];
                xv.x = fmaxf((xv.x - m.x) * iv.x, 0.0f);
                xv.y = fmaxf((xv.y - m.y) * iv.y, 0.0f);
                xv.z = fmaxf((xv.z - m.z) * iv.z, 0.0f);
                xv.w = fmaxf((xv.w - m.w) * iv.w, 0.0f);
            }
#pragma unroll
            for (int o = 0; o < CPT; ++o) {
                float4 wv = W4[(size_t)(obase + o) * K4 + k4];   // uniform -> s_load
                acc[o] = fmaf(xv.x, wv.x, acc[o]);
                acc[o] = fmaf(xv.y, wv.y, acc[o]);
                acc[o] = fmaf(xv.z, wv.z, acc[o]);
                acc[o] = fmaf(xv.w, wv.w, acc[o]);
            }
        }
        float hn[(BLEND || H0OUT) ? CPT : 1];
        if (BLEND || H0OUT) {
#pragma unroll
            for (int o4 = 0; o4 < CPT / 4; ++o4) {
                float4 xb = X4[(size_t)nc * K4 + obase / 4 + o4];
                float4 m  = *(const float4*)&muin[obase + o4 * 4];
                float4 iv = *(const float4*)&invin[obase + o4 * 4];
                hn[o4 * 4 + 0] = fmaxf((xb.x - m.x) * iv.x, 0.0f);
                hn[o4 * 4 + 1] = fmaxf((xb.y - m.y) * iv.y, 0.0f);
                hn[o4 * 4 + 2] = fmaxf((xb.z - m.z) * iv.z, 0.0f);
                hn[o4 * 4 + 3] = fmaxf((xb.w - m.w) * iv.w, 0.0f);
            }
        }
        if (BLEND) {
#pragma unroll
            for (int o = 0; o < CPT; ++o) acc[o] = (1.0f - beta) * hn[o] + beta * acc[o];
        }
        if (valid) {
            if (PACKOUT) {
                unsigned* ob = outb + (size_t)n * (C / 2) + obase / 2;
#pragma unroll
                for (int o4 = 0; o4 < CPT / 4; ++o4) {
                    uint2 pk;
                    pk.x = packbf(acc[o4 * 4 + 0], acc[o4 * 4 + 1]);
                    pk.y = packbf(acc[o4 * 4 + 2], acc[o4 * 4 + 3]);
                    *(uint2*)(ob + o4 * 2) = pk;
                }
            } else {
#pragma unroll
                for (int o4 = 0; o4 < CPT / 4; ++o4) {
                    *(float4*)&outf[(size_t)n * C + obase + o4 * 4] =
                        make_float4(acc[o4 * 4], acc[o4 * 4 + 1], acc[o4 * 4 + 2], acc[o4 * 4 + 3]);
                }
            }
            if (H0OUT) {
                unsigned* hb = h0n + (size_t)n * (C / 2) + obase / 2;
#pragma unroll
                for (int o4 = 0; o4 < CPT / 4; ++o4) {
                    uint2 pk;
                    pk.x = packbf(hn[o4 * 4 + 0], hn[o4 * 4 + 1]);
                    pk.y = packbf(hn[o4 * 4 + 2], hn[o4 * 4 + 3]);
                    *(uint2*)(hb + o4 * 2) = pk;
                }
            }
        }
        if (STATS) {
#pragma unroll
            for (int o = 0; o < CPT; ++o) {
                float s = acc[o], q = acc[o] * acc[o];
#pragma unroll
                for (int d = 1; d < 64; d <<= 1) { s += __shfl_xor(s, d); q += __shfl_xor(q, d); }
                if (lane == 0) {
                    atomicAdd(&osum[obase + o], s);
                    atomicAdd(&osq[obase + o], q);
                }
            }
        }
    }
}

// ---------------- SpMM v3: bf16 gather table ----------------
// LAYER: out = 0.9*(selfw*t + sum w*t[col]) + 0.1*h0n; else plain spmm.

template <int C, bool LAYER, bool STATS>
__global__ __launch_bounds__(256) void spmm3(
    const uint2* __restrict__ tb, const uint2* __restrict__ h0n,
    const int* __restrict__ row_start, const int2* __restrict__ cw,
    const float* __restrict__ selfw, float4* __restrict__ outf,
    float* __restrict__ osum, float* __restrict__ osq) {
    constexpr int C4 = C / 4;
    __shared__ float ssum[STATS ? C : 1];
    __shared__ float ssq[STATS ? C : 1];
    const int tid = threadIdx.x;
    if (STATS) {
        if (tid < C) { ssum[tid] = 0.0f; ssq[tid] = 0.0f; }
        __syncthreads();
    }
    const int total = N_NODES * C4;
    for (int idx = blockIdx.x * 256 + tid; idx < total; idx += gridDim.x * 256) {
        const int n = idx / C4;
        const int c4 = idx - n * C4;
        const float sw = selfw[n];
        float4 acc = unpack4(tb[idx]);
        acc.x *= sw; acc.y *= sw; acc.z *= sw; acc.w *= sw;
        const int rs = row_start[n], re = row_start[n + 1];
        int j = rs;
        for (; j + 3 < re; j += 4) {
            int2 e0 = cw[j], e1 = cw[j + 1], e2 = cw[j + 2], e3 = cw[j + 3];
            uint2 p0 = tb[(size_t)e0.x * C4 + c4];
            uint2 p1 = tb[(size_t)e1.x * C4 + c4];
            uint2 p2 = tb[(size_t)e2.x * C4 + c4];
            uint2 p3 = tb[(size_t)e3.x * C4 + c4];
            float w0 = __int_as_float(e0.y), w1 = __int_as_float(e1.y);
            float w2 = __int_as_float(e2.y), w3 = __int_as_float(e3.y);
            float4 a0 = unpack4(p0), a1 = unpack4(p1), a2 = unpack4(p2), a3 = unpack4(p3);
            acc.x = fmaf(w0, a0.x, acc.x); acc.y = fmaf(w0, a0.y, acc.y);
            acc.z = fmaf(w0, a0.z, acc.z); acc.w = fmaf(w0, a0.w, acc.w);
            acc.x = fmaf(w1, a1.x, acc.x); acc.y = fmaf(w1, a1.y, acc.y);
            acc.z = fmaf(w1, a1.z, acc.z); acc.w = fmaf(w1, a1.w, acc.w);
            acc.x = fmaf(w2, a2.x, acc.x); acc.y = fmaf(w2, a2.y, acc.y);
            acc.z = fmaf(w2, a2.z, acc.z); acc.w = fmaf(w2, a2.w, acc.w);
            acc.x = fmaf(w3, a3.x, acc.x); acc.y = fmaf(w3, a3.y, acc.y);
            acc.z = fmaf(w3, a3.z, acc.z); acc.w = fmaf(w3, a3.w, acc.w);
        }
        for (; j < re; ++j) {
            int2 e0 = cw[j];
            uint2 p0 = tb[(size_t)e0.x * C4 + c4];
            float w0 = __int_as_float(e0.y);
            float4 a0 = unpack4(p0);
            acc.x = fmaf(w0, a0.x, acc.x); acc.y = fmaf(w0, a0.y, acc.y);
            acc.z = fmaf(w0, a0.z, acc.z); acc.w = fmaf(w0, a0.w, acc.w);
        }
        if (LAYER) {
            float4 h0 = unpack4(h0n[idx]);
            acc.x = 0.9f * acc.x + 0.1f * h0.x;
            acc.y = 0.9f * acc.y + 0.1f * h0.y;
            acc.z = 0.9f * acc.z + 0.1f * h0.z;
            acc.w = 0.9f * acc.w + 0.1f * h0.w;
        }
        outf[idx] = acc;
        if (STATS) {
            int c = c4 * 4;
            atomicAdd(&ssum[c + 0], acc.x); atomicAdd(&ssq[c + 0], acc.x * acc.x);
            atomicAdd(&ssum[c + 1], acc.y); atomicAdd(&ssq[c + 1], acc.y * acc.y);
            atomicAdd(&ssum[c + 2], acc.z); atomicAdd(&ssq[c + 2], acc.z * acc.z);
            atomicAdd(&ssum[c + 3], acc.w); atomicAdd(&ssq[c + 3], acc.w * acc.w);
        }
    }
    if (STATS) {
        __syncthreads();
        if (tid < C) {
            atomicAdd(&osum[tid], ssum[tid]);
            atomicAdd(&osq[tid], ssq[tid]);
        }
    }
}

// ---------------- launch ----------------

extern "C" void kernel_launch(void* const* d_in, const int* in_sizes, int n_in,
                              void* d_out, int out_size, void* d_ws, size_t ws_size,
                              hipStream_t stream) {
    const float* x  = (const float*)d_in[0];
    const int*   ei = (const int*)d_in[1];
    const float* W0 = (const float*)d_in[2];
    const float* W1 = (const float*)d_in[3];
    const float* W2 = (const float*)d_in[4];
    const float* W3 = (const float*)d_in[5];
    float* out = (float*)d_out;

    char* w = (char*)d_ws;
    auto alloc = [&](size_t bytes) {
        void* p = (void*)w;
        w += (bytes + 255) & ~(size_t)255;
        return p;
    };
    int*      cnt       = (int*)alloc(N_NODES * 4);
    int*      row_start = (int*)alloc((N_NODES + 1) * 4);
    int*      fillp     = (int*)alloc(N_NODES * 4);
    int2*     cw        = (int2*)alloc((size_t)N_EDGES * 8);
    float*    dinv      = (float*)alloc(N_NODES * 4);
    float*    selfw     = (float*)alloc(N_NODES * 4);
    float*    g0        = (float*)alloc((size_t)N_NODES * HID_CH * 4);
    float*    s         = (float*)alloc((size_t)N_NODES * HID_CH * 4);
    unsigned* tb        = (unsigned*)alloc((size_t)N_NODES * (HID_CH / 2) * 4);
    unsigned* h0n       = (unsigned*)alloc((size_t)N_NODES * (HID_CH / 2) * 4);
    float*    stats     = (float*)alloc(6 * HID_CH * 4);
    float*    mu0  = (float*)alloc(HID_CH * 4);
    float*    inv0 = (float*)alloc(HID_CH * 4);
    float*    mu1  = (float*)alloc(HID_CH * 4);
    float*    inv1 = (float*)alloc(HID_CH * 4);
    float*    mu2  = (float*)alloc(HID_CH * 4);
    float*    inv2 = (float*)alloc(HID_CH * 4);
    float* sums0 = stats,              * sq0 = stats + HID_CH;
    float* sums1 = stats + 2 * HID_CH, * sq1 = stats + 3 * HID_CH;
    float* sums2 = stats + 4 * HID_CH, * sq2 = stats + 5 * HID_CH;

    const int EB = (N_EDGES + 255) / 256;
    const int NB = (N_NODES + 255) / 256;
    const int G96 = ((N_NODES + 63) / 64) * 6 / 4 + 1;   // 782*6 waves -> 1174 blocks
    const int G40 = ((N_NODES + 63) / 64) * 2 / 4 + 1;   // 782*2 waves -> 392 blocks

    hipMemsetAsync(cnt, 0, N_NODES * 4, stream);
    hipMemsetAsync(fillp, 0, N_NODES * 4, stream);
    hipMemsetAsync(stats, 0, 6 * HID_CH * 4, stream);

    count_kernel<<<EB, 256, 0, stream>>>(ei, cnt);
    norm_kernel<<<NB, 256, 0, stream>>>(cnt, dinv, selfw);
    scan_kernel<<<1, 256, 0, stream>>>(cnt, row_start);
    fill_kernel<<<EB, 256, 0, stream>>>(ei, row_start, fillp, dinv, cw);

    // layer 0: g0 = x @ W0^T (fp32) + stats0
    gemm3<IN_CH, HID_CH, 16, false, false, true, false, false><<<G96, 256, 0, stream>>>(
        x, W0, g0, nullptr, nullptr, nullptr, nullptr, sums0, sq0, 0.0f);
    bn_fin<<<1, HID_CH, 0, stream>>>(sums0, sq0, mu0, inv0);

    // layer 1: tb = bf16(blend(hn0, hn0@W1^T, .5)); h0n = bf16(hn0)
    gemm3<HID_CH, HID_CH, 16, true, true, false, true, true><<<G96, 256, 0, stream>>>(
        g0, W1, nullptr, tb, h0n, mu0, inv0, nullptr, nullptr, 0.5f);
    spmm3<HID_CH, true, true><<<2048, 256, 0, stream>>>(
        (const uint2*)tb, (const uint2*)h0n, row_start, cw, selfw, (float4*)s, sums1, sq1);
    bn_fin<<<1, HID_CH, 0, stream>>>(sums1, sq1, mu1, inv1);

    // layer 2: tb = bf16(blend(hn1, hn1@W2^T, .25))
    gemm3<HID_CH, HID_CH, 16, true, true, false, true, false><<<G96, 256, 0, stream>>>(
        s, W2, nullptr, tb, nullptr, mu1, inv1, nullptr, nullptr, 0.25f);
    spmm3<HID_CH, true, true><<<2048, 256, 0, stream>>>(
        (const uint2*)tb, (const uint2*)h0n, row_start, cw, selfw, (float4*)s, sums2, sq2);
    bn_fin<<<1, HID_CH, 0, stream>>>(sums2, sq2, mu2, inv2);

    // final: tb = bf16(hn2 @ W3^T); out = spmm(tb)
    gemm3<HID_CH, OUT_CH, 20, false, true, false, true, false><<<G40, 256, 0, stream>>>(
        s, W3, nullptr, tb, nullptr, mu2, inv2, nullptr, nullptr, 0.0f);
    spmm3<OUT_CH, false, false><<<1954, 256, 0, stream>>>(
        (const uint2*)tb, nullptr, row_start, cw, selfw, (float4*)out, nullptr, nullptr);
}

// Round 5
// 861.349 us; speedup vs baseline: 1.2342x; 1.2342x over previous
//
#include <hip/hip_runtime.h>

#define N_NODES 50000
#define N_EDGES 800000
#define IN_CH 128
#define HID_CH 96
#define OUT_CH 40
#define EPS 1e-5f

// ---------------- bf16 pack/unpack ----------------

__device__ __forceinline__ unsigned packbf(float a, float b) {
    unsigned ua = __float_as_uint(a), ub = __float_as_uint(b);
    ua += 0x7fffu + ((ua >> 16) & 1u);           // RTNE
    ub += 0x7fffu + ((ub >> 16) & 1u);
    return (ua >> 16) | (ub & 0xffff0000u);
}

__device__ __forceinline__ float4 unpack4(uint2 v) {
    return make_float4(__uint_as_float(v.x << 16), __uint_as_float(v.x & 0xffff0000u),
                       __uint_as_float(v.y << 16), __uint_as_float(v.y & 0xffff0000u));
}

// ---------------- CSR build ----------------

__global__ void count_kernel(const int* __restrict__ ei, int* __restrict__ cnt) {
    int e = blockIdx.x * blockDim.x + threadIdx.x;
    if (e >= N_EDGES) return;
    int s = ei[e], d = ei[N_EDGES + e];
    if (s != d) atomicAdd(&cnt[d], 1);
}

__global__ void norm_kernel(const int* __restrict__ cnt, float* __restrict__ dinv,
                            float* __restrict__ selfw) {
    int n = blockIdx.x * blockDim.x + threadIdx.x;
    if (n >= N_NODES) return;
    float deg = (float)(cnt[n] + 1);
    dinv[n]  = rsqrtf(deg);
    selfw[n] = 1.0f / deg;
}

__global__ void scan_kernel(const int* __restrict__ cnt, int* __restrict__ row_start) {
    __shared__ int partial[256];
    const int T = 256;
    int tid = threadIdx.x;
    int seg = (N_NODES + T - 1) / T;
    int s0 = tid * seg;
    int s1 = s0 + seg; if (s1 > N_NODES) s1 = N_NODES;
    int sum = 0;
    for (int i = s0; i < s1; i++) sum += cnt[i];
    partial[tid] = sum;
    __syncthreads();
    if (tid == 0) {
        int acc = 0;
        for (int i = 0; i < T; i++) { int v = partial[i]; partial[i] = acc; acc += v; }
    }
    __syncthreads();
    int acc = partial[tid];
    for (int i = s0; i < s1; i++) { row_start[i] = acc; acc += cnt[i]; }
    if (tid == T - 1) row_start[N_NODES] = acc;
}

__global__ void fill_kernel(const int* __restrict__ ei, const int* __restrict__ row_start,
                            int* __restrict__ fillp, const float* __restrict__ dinv,
                            int2* __restrict__ cw) {
    int e = blockIdx.x * blockDim.x + threadIdx.x;
    if (e >= N_EDGES) return;
    int s = ei[e], d = ei[N_EDGES + e];
    if (s == d) return;
    int p = atomicAdd(&fillp[d], 1);
    int idx = row_start[d] + p;
    cw[idx] = make_int2(s, __float_as_int(dinv[s] * dinv[d]));
}

__global__ void bn_fin(const float* __restrict__ sums, const float* __restrict__ sq,
                       float* __restrict__ mu, float* __restrict__ inv) {
    int c = threadIdx.x;
    if (c >= HID_CH) return;
    float m = sums[c] * (1.0f / N_NODES);
    float v = sq[c] * (1.0f / N_NODES) - m * m;
    mu[c] = m; inv[c] = rsqrtf(v + EPS);
}

// ---------------- GEMM v4: X tile in LDS (coalesced, one pass), W via uniform s_load --------
// Block = 256 thr = 4 waves, handles RPB rows x all C channels.
// PARTS = C/CPT waves per row-group; RG = 4/PARTS row-groups of 64 rows each; RPB = RG*64.
// NORMX: BN+ReLU applied when staging X into LDS (so LDS holds hn; BLEND re-reads it free).
// STATS: butterfly-reduce acc -> global atomics (gemm0). PACKOUT: bf16 out. H0OUT: bf16 hn out.

template <int K, int C, int CPT, bool BLEND, bool NORMX, bool STATS, bool PACKOUT, bool H0OUT>
__global__ __launch_bounds__(256) void gemm4(
    const float* __restrict__ X, const float* __restrict__ W,
    float* __restrict__ outf, unsigned* __restrict__ outb, unsigned* __restrict__ h0n,
    const float* __restrict__ muin, const float* __restrict__ invin,
    float* __restrict__ osum, float* __restrict__ osq, float beta) {
    constexpr int PARTS = C / CPT;            // waves per 64-row group
    constexpr int RG = 4 / PARTS;             // row-groups per block
    constexpr int RPB = RG * 64;              // rows per block
    constexpr int K4 = K / 4;
    constexpr int KP = K + 4;                 // LDS row stride (floats): bank-group spread
    __shared__ float sX[RPB * KP];
    const int tid = threadIdx.x;
    const int lane = tid & 63;
    const int wid = __builtin_amdgcn_readfirstlane(tid >> 6);   // uniform -> SGPR
    const int rg = wid / PARTS;
    const int obase = (wid - rg * PARTS) * CPT;                 // uniform
    const int nbase = blockIdx.x * RPB;

    // ---- cooperative coalesced stage: X[nbase..nbase+RPB) -> LDS (normalized if NORMX)
    const float4* X4 = (const float4*)X;
    for (int i = tid; i < RPB * K4; i += 256) {
        int r = i / K4, k4 = i - r * K4;
        int n = nbase + r;
        float4 v = make_float4(0.f, 0.f, 0.f, 0.f);
        if (n < N_NODES) v = X4[(size_t)n * K4 + k4];
        if (NORMX) {
            float4 m  = *(const float4*)&muin[k4 * 4];
            float4 iv = *(const float4*)&invin[k4 * 4];
            v.x = fmaxf((v.x - m.x) * iv.x, 0.0f);
            v.y = fmaxf((v.y - m.y) * iv.y, 0.0f);
            v.z = fmaxf((v.z - m.z) * iv.z, 0.0f);
            v.w = fmaxf((v.w - m.w) * iv.w, 0.0f);
        }
        *(float4*)&sX[r * KP + k4 * 4] = v;
    }
    __syncthreads();

    const int r = rg * 64 + lane;
    const int n = nbase + r;
    float acc[CPT];
#pragma unroll
    for (int o = 0; o < CPT; o++) acc[o] = 0.0f;
    const float4* W4 = (const float4*)W;
    for (int k4 = 0; k4 < K4; ++k4) {
        float4 xv = *(const float4*)&sX[r * KP + k4 * 4];
#pragma unroll
        for (int o = 0; o < CPT; ++o) {
            float4 wv = W4[(size_t)(obase + o) * K4 + k4];      // uniform -> s_load_dwordx4
            acc[o] = fmaf(xv.x, wv.x, acc[o]);
            acc[o] = fmaf(xv.y, wv.y, acc[o]);
            acc[o] = fmaf(xv.z, wv.z, acc[o]);
            acc[o] = fmaf(xv.w, wv.w, acc[o]);
        }
    }
    if (BLEND) {
        // LDS already holds hn (NORMX staging); channels obase..obase+CPT <= K
#pragma unroll
        for (int o = 0; o < CPT; ++o)
            acc[o] = (1.0f - beta) * sX[r * KP + obase + o] + beta * acc[o];
    }
    if (n < N_NODES) {
        if (PACKOUT) {
            unsigned* ob = outb + (size_t)n * (C / 2) + obase / 2;
#pragma unroll
            for (int o4 = 0; o4 < CPT / 4; ++o4) {
                uint2 pk;
                pk.x = packbf(acc[o4 * 4 + 0], acc[o4 * 4 + 1]);
                pk.y = packbf(acc[o4 * 4 + 2], acc[o4 * 4 + 3]);
                *(uint2*)(ob + o4 * 2) = pk;
            }
        } else {
#pragma unroll
            for (int o4 = 0; o4 < CPT / 4; ++o4)
                *(float4*)&outf[(size_t)n * C + obase + o4 * 4] =
                    make_float4(acc[o4 * 4], acc[o4 * 4 + 1], acc[o4 * 4 + 2], acc[o4 * 4 + 3]);
        }
        if (H0OUT) {
            unsigned* hb = h0n + (size_t)n * (C / 2) + obase / 2;
#pragma unroll
            for (int o4 = 0; o4 < CPT / 4; ++o4) {
                uint2 pk;
                pk.x = packbf(sX[r * KP + obase + o4 * 4 + 0], sX[r * KP + obase + o4 * 4 + 1]);
                pk.y = packbf(sX[r * KP + obase + o4 * 4 + 2], sX[r * KP + obase + o4 * 4 + 3]);
                *(uint2*)(hb + o4 * 2) = pk;
            }
        }
    }
    if (STATS) {
#pragma unroll
        for (int o = 0; o < CPT; ++o) {
            float s = acc[o], q = acc[o] * acc[o];
#pragma unroll
            for (int d = 1; d < 64; d <<= 1) { s += __shfl_xor(s, d); q += __shfl_xor(q, d); }
            if (lane == 0) {
                atomicAdd(&osum[obase + o], s);
                atomicAdd(&osq[obase + o], q);
            }
        }
    }
}

// ---------------- SpMM v3: bf16 gather table ----------------

template <int C, bool LAYER, bool STATS>
__global__ __launch_bounds__(256) void spmm3(
    const uint2* __restrict__ tb, const uint2* __restrict__ h0n,
    const int* __restrict__ row_start, const int2* __restrict__ cw,
    const float* __restrict__ selfw, float4* __restrict__ outf,
    float* __restrict__ osum, float* __restrict__ osq) {
    constexpr int C4 = C / 4;
    __shared__ float ssum[STATS ? C : 1];
    __shared__ float ssq[STATS ? C : 1];
    const int tid = threadIdx.x;
    if (STATS) {
        if (tid < C) { ssum[tid] = 0.0f; ssq[tid] = 0.0f; }
        __syncthreads();
    }
    const int total = N_NODES * C4;
    for (int idx = blockIdx.x * 256 + tid; idx < total; idx += gridDim.x * 256) {
        const int n = idx / C4;
        const int c4 = idx - n * C4;
        const float sw = selfw[n];
        float4 acc = unpack4(tb[idx]);
        acc.x *= sw; acc.y *= sw; acc.z *= sw; acc.w *= sw;
        const int rs = row_start[n], re = row_start[n + 1];
        int j = rs;
        for (; j + 3 < re; j += 4) {
            int2 e0 = cw[j], e1 = cw[j + 1], e2 = cw[j + 2], e3 = cw[j + 3];
            uint2 p0 = tb[(size_t)e0.x * C4 + c4];
            uint2 p1 = tb[(size_t)e1.x * C4 + c4];
            uint2 p2 = tb[(size_t)e2.x * C4 + c4];
            uint2 p3 = tb[(size_t)e3.x * C4 + c4];
            float w0 = __int_as_float(e0.y), w1 = __int_as_float(e1.y);
            float w2 = __int_as_float(e2.y), w3 = __int_as_float(e3.y);
            float4 a0 = unpack4(p0), a1 = unpack4(p1), a2 = unpack4(p2), a3 = unpack4(p3);
            acc.x = fmaf(w0, a0.x, acc.x); acc.y = fmaf(w0, a0.y, acc.y);
            acc.z = fmaf(w0, a0.z, acc.z); acc.w = fmaf(w0, a0.w, acc.w);
            acc.x = fmaf(w1, a1.x, acc.x); acc.y = fmaf(w1, a1.y, acc.y);
            acc.z = fmaf(w1, a1.z, acc.z); acc.w = fmaf(w1, a1.w, acc.w);
            acc.x = fmaf(w2, a2.x, acc.x); acc.y = fmaf(w2, a2.y, acc.y);
            acc.z = fmaf(w2, a2.z, acc.z); acc.w = fmaf(w2, a2.w, acc.w);
            acc.x = fmaf(w3, a3.x, acc.x); acc.y = fmaf(w3, a3.y, acc.y);
            acc.z = fmaf(w3, a3.z, acc.z); acc.w = fmaf(w3, a3.w, acc.w);
        }
        for (; j < re; ++j) {
            int2 e0 = cw[j];
            uint2 p0 = tb[(size_t)e0.x * C4 + c4];
            float w0 = __int_as_float(e0.y);
            float4 a0 = unpack4(p0);
            acc.x = fmaf(w0, a0.x, acc.x); acc.y = fmaf(w0, a0.y, acc.y);
            acc.z = fmaf(w0, a0.z, acc.z); acc.w = fmaf(w0, a0.w, acc.w);
        }
        if (LAYER) {
            float4 h0 = unpack4(h0n[idx]);
            acc.x = 0.9f * acc.x + 0.1f * h0.x;
            acc.y = 0.9f * acc.y + 0.1f * h0.y;
            acc.z = 0.9f * acc.z + 0.1f * h0.z;
            acc.w = 0.9f * acc.w + 0.1f * h0.w;
        }
        outf[idx] = acc;
        if (STATS) {
            int c = c4 * 4;
            atomicAdd(&ssum[c + 0], acc.x); atomicAdd(&ssq[c + 0], acc.x * acc.x);
            atomicAdd(&ssum[c + 1], acc.y); atomicAdd(&ssq[c + 1], acc.y * acc.y);
            atomicAdd(&ssum[c + 2], acc.z); atomicAdd(&ssq[c + 2], acc.z * acc.z);
            atomicAdd(&ssum[c + 3], acc.w); atomicAdd(&ssq[c + 3], acc.w * acc.w);
        }
    }
    if (STATS) {
        __syncthreads();
        if (tid < C) {
            atomicAdd(&osum[tid], ssum[tid]);
            atomicAdd(&osq[tid], ssq[tid]);
        }
    }
}

// ---------------- launch ----------------

extern "C" void kernel_launch(void* const* d_in, const int* in_sizes, int n_in,
                              void* d_out, int out_size, void* d_ws, size_t ws_size,
                              hipStream_t stream) {
    const float* x  = (const float*)d_in[0];
    const int*   ei = (const int*)d_in[1];
    const float* W0 = (const float*)d_in[2];
    const float* W1 = (const float*)d_in[3];
    const float* W2 = (const float*)d_in[4];
    const float* W3 = (const float*)d_in[5];
    float* out = (float*)d_out;

    char* w = (char*)d_ws;
    auto alloc = [&](size_t bytes) {
        void* p = (void*)w;
        w += (bytes + 255) & ~(size_t)255;
        return p;
    };
    int*      cnt       = (int*)alloc(N_NODES * 4);
    int*      row_start = (int*)alloc((N_NODES + 1) * 4);
    int*      fillp     = (int*)alloc(N_NODES * 4);
    int2*     cw        = (int2*)alloc((size_t)N_EDGES * 8);
    float*    dinv      = (float*)alloc(N_NODES * 4);
    float*    selfw     = (float*)alloc(N_NODES * 4);
    float*    g0        = (float*)alloc((size_t)N_NODES * HID_CH * 4);
    float*    s         = (float*)alloc((size_t)N_NODES * HID_CH * 4);
    unsigned* tb        = (unsigned*)alloc((size_t)N_NODES * (HID_CH / 2) * 4);
    unsigned* h0n       = (unsigned*)alloc((size_t)N_NODES * (HID_CH / 2) * 4);
    float*    stats     = (float*)alloc(6 * HID_CH * 4);
    float*    mu0  = (float*)alloc(HID_CH * 4);
    float*    inv0 = (float*)alloc(HID_CH * 4);
    float*    mu1  = (float*)alloc(HID_CH * 4);
    float*    inv1 = (float*)alloc(HID_CH * 4);
    float*    mu2  = (float*)alloc(HID_CH * 4);
    float*    inv2 = (float*)alloc(HID_CH * 4);
    float* sums0 = stats,              * sq0 = stats + HID_CH;
    float* sums1 = stats + 2 * HID_CH, * sq1 = stats + 3 * HID_CH;
    float* sums2 = stats + 4 * HID_CH, * sq2 = stats + 5 * HID_CH;

    const int EB = (N_EDGES + 255) / 256;
    const int NB = (N_NODES + 255) / 256;
    const int GB64  = (N_NODES + 63) / 128 * 2 + 1;   // not used
    const int G64   = (N_NODES + 63) / 64;            // 782 blocks (64 rows each)
    const int G128  = (N_NODES + 127) / 128;          // 391 blocks (128 rows each)

    hipMemsetAsync(cnt, 0, N_NODES * 4, stream);
    hipMemsetAsync(fillp, 0, N_NODES * 4, stream);
    hipMemsetAsync(stats, 0, 6 * HID_CH * 4, stream);

    count_kernel<<<EB, 256, 0, stream>>>(ei, cnt);
    norm_kernel<<<NB, 256, 0, stream>>>(cnt, dinv, selfw);
    scan_kernel<<<1, 256, 0, stream>>>(cnt, row_start);
    fill_kernel<<<EB, 256, 0, stream>>>(ei, row_start, fillp, dinv, cw);

    // layer 0: g0 = x @ W0^T (fp32) + stats0
    gemm4<IN_CH, HID_CH, 24, false, false, true, false, false><<<G64, 256, 0, stream>>>(
        x, W0, g0, nullptr, nullptr, nullptr, nullptr, sums0, sq0, 0.0f);
    bn_fin<<<1, HID_CH, 0, stream>>>(sums0, sq0, mu0, inv0);

    // layer 1: tb = bf16(blend(hn0, hn0@W1^T, .5)); h0n = bf16(hn0)
    gemm4<HID_CH, HID_CH, 24, true, true, false, true, true><<<G64, 256, 0, stream>>>(
        g0, W1, nullptr, tb, h0n, mu0, inv0, nullptr, nullptr, 0.5f);
    spmm3<HID_CH, true, true><<<2048, 256, 0, stream>>>(
        (const uint2*)tb, (const uint2*)h0n, row_start, cw, selfw, (float4*)s, sums1, sq1);
    bn_fin<<<1, HID_CH, 0, stream>>>(sums1, sq1, mu1, inv1);

    // layer 2: tb = bf16(blend(hn1, hn1@W2^T, .25))
    gemm4<HID_CH, HID_CH, 24, true, true, false, true, false><<<G64, 256, 0, stream>>>(
        s, W2, nullptr, tb, nullptr, mu1, inv1, nullptr, nullptr, 0.25f);
    spmm3<HID_CH, true, true><<<2048, 256, 0, stream>>>(
        (const uint2*)tb, (const uint2*)h0n, row_start, cw, selfw, (float4*)s, sums2, sq2);
    bn_fin<<<1, HID_CH, 0, stream>>>(sums2, sq2, mu2, inv2);

    // final: tb = bf16(hn2 @ W3^T); out = spmm(tb)
    gemm4<HID_CH, OUT_CH, 20, false, true, false, true, false><<<G128, 256, 0, stream>>>(
        s, W3, nullptr, tb, nullptr, mu2, inv2, nullptr, nullptr, 0.0f);
    spmm3<OUT_CH, false, false><<<1954, 256, 0, stream>>>(
        (const uint2*)tb, nullptr, row_start, cw, selfw, (float4*)out, nullptr, nullptr);
    (void)GB64;
}

// Round 6
// 782.798 us; speedup vs baseline: 1.3580x; 1.1003x over previous
//
#include <hip/hip_runtime.h>

#define N_NODES 50000
#define N_EDGES 800000
#define IN_CH 128
#define HID_CH 96
#define OUT_CH 40
#define EPS 1e-5f

// ---------------- bf16 pack/unpack ----------------

__device__ __forceinline__ unsigned packbf(float a, float b) {
    unsigned ua = __float_as_uint(a), ub = __float_as_uint(b);
    ua += 0x7fffu + ((ua >> 16) & 1u);           // RTNE
    ub += 0x7fffu + ((ub >> 16) & 1u);
    return (ua >> 16) | (ub & 0xffff0000u);
}

__device__ __forceinline__ float4 unpack4(uint2 v) {
    return make_float4(__uint_as_float(v.x << 16), __uint_as_float(v.x & 0xffff0000u),
                       __uint_as_float(v.y << 16), __uint_as_float(v.y & 0xffff0000u));
}

// ---------------- CSR build ----------------

__global__ void count_kernel(const int* __restrict__ ei, int* __restrict__ cnt) {
    int e = blockIdx.x * blockDim.x + threadIdx.x;
    if (e >= N_EDGES) return;
    int s = ei[e], d = ei[N_EDGES + e];
    if (s != d) atomicAdd(&cnt[d], 1);
}

__global__ void norm_kernel(const int* __restrict__ cnt, float* __restrict__ dinv,
                            float* __restrict__ selfw) {
    int n = blockIdx.x * blockDim.x + threadIdx.x;
    if (n >= N_NODES) return;
    float deg = (float)(cnt[n] + 1);
    dinv[n]  = rsqrtf(deg);
    selfw[n] = 1.0f / deg;
}

__global__ void scan_kernel(const int* __restrict__ cnt, int* __restrict__ row_start) {
    __shared__ int partial[256];
    const int T = 256;
    int tid = threadIdx.x;
    int seg = (N_NODES + T - 1) / T;
    int s0 = tid * seg;
    int s1 = s0 + seg; if (s1 > N_NODES) s1 = N_NODES;
    int sum = 0;
    for (int i = s0; i < s1; i++) sum += cnt[i];
    partial[tid] = sum;
    __syncthreads();
    if (tid == 0) {
        int acc = 0;
        for (int i = 0; i < T; i++) { int v = partial[i]; partial[i] = acc; acc += v; }
    }
    __syncthreads();
    int acc = partial[tid];
    for (int i = s0; i < s1; i++) { row_start[i] = acc; acc += cnt[i]; }
    if (tid == T - 1) row_start[N_NODES] = acc;
}

__global__ void fill_kernel(const int* __restrict__ ei, const int* __restrict__ row_start,
                            int* __restrict__ fillp, const float* __restrict__ dinv,
                            int2* __restrict__ cw) {
    int e = blockIdx.x * blockDim.x + threadIdx.x;
    if (e >= N_EDGES) return;
    int s = ei[e], d = ei[N_EDGES + e];
    if (s == d) return;
    int p = atomicAdd(&fillp[d], 1);
    int idx = row_start[d] + p;
    cw[idx] = make_int2(s, __float_as_int(dinv[s] * dinv[d]));
}

__global__ void bn_fin(const float* __restrict__ sums, const float* __restrict__ sq,
                       float* __restrict__ mu, float* __restrict__ inv) {
    int c = threadIdx.x;
    if (c >= HID_CH) return;
    float m = sums[c] * (1.0f / N_NODES);
    float v = sq[c] * (1.0f / N_NODES) - m * m;
    mu[c] = m; inv[c] = rsqrtf(v + EPS);
}

// ---------------- GEMM v5: W AND X both in LDS, no scalar/global loads in loop ----------
// 256 threads: ob = tid & (NCT-1) channel-lane (channels ob + NCT*j, j<CJ, strided);
// rl = tid / NCT row-lane (rows rl + RT*t, t<NT). Per k4: NT+CJ ds_read_b128 -> NT*CJ*4 FMA.
// CSPLIT: split C across CSPLIT block-groups (gemm0 LDS fit). NORMX: BN+ReLU at X-stage.
// BLEND: GCNII identity blend from sX (requires CSPLIT==1, C<=K). PACKOUT/H0OUT: bf16 out,
// adjacent-channel pairs assembled via __shfl_xor(.,1). STATS: butterfly + atomics.

template <int K, int C, int NCT, int CJ, int NT, int CSPLIT,
          bool BLEND, bool NORMX, bool STATS, bool PACKOUT, bool H0OUT>
__global__ __launch_bounds__(256) void gemm5(
    const float* __restrict__ X, const float* __restrict__ W,
    float* __restrict__ outf, unsigned* __restrict__ outb, unsigned* __restrict__ h0n,
    const float* __restrict__ muin, const float* __restrict__ invin,
    float* __restrict__ osum, float* __restrict__ osq, float beta) {
    constexpr int K4 = K / 4;
    constexpr int KP = K + 4;                 // LDS row stride (floats)
    constexpr int CG = C / CSPLIT;            // channels per block
    constexpr int RT = 256 / NCT;             // row-threads
    constexpr int RPB = RT * NT;              // rows per block
    __shared__ float sW[CG * KP];
    __shared__ float sX[RPB * KP];
    const int tid = threadIdx.x;
    const int ob = tid & (NCT - 1);
    const int rl = tid / NCT;
    const int grp = (CSPLIT > 1) ? ((int)blockIdx.x % CSPLIT) : 0;
    const int nb  = (CSPLIT > 1) ? ((int)blockIdx.x / CSPLIT) : (int)blockIdx.x;
    const int cbase = grp * CG;
    const int nbase = nb * RPB;
    const float4* X4 = (const float4*)X;
    const float4* W4 = (const float4*)W;

    // stage W tile
    for (int i = tid; i < CG * K4; i += 256) {
        int o = i / K4, k4 = i - o * K4;
        *(float4*)&sW[o * KP + k4 * 4] = W4[(size_t)(cbase + o) * K4 + k4];
    }
    // stage X tile (normalized+ReLU if NORMX)
    for (int i = tid; i < RPB * K4; i += 256) {
        int r = i / K4, k4 = i - r * K4;
        int n = nbase + r;
        float4 v = make_float4(0.f, 0.f, 0.f, 0.f);
        if (n < N_NODES) v = X4[(size_t)n * K4 + k4];
        if (NORMX) {
            float4 m  = *(const float4*)&muin[k4 * 4];
            float4 iv = *(const float4*)&invin[k4 * 4];
            v.x = fmaxf((v.x - m.x) * iv.x, 0.0f);
            v.y = fmaxf((v.y - m.y) * iv.y, 0.0f);
            v.z = fmaxf((v.z - m.z) * iv.z, 0.0f);
            v.w = fmaxf((v.w - m.w) * iv.w, 0.0f);
        }
        *(float4*)&sX[r * KP + k4 * 4] = v;
    }
    __syncthreads();

    float acc[NT][CJ];
#pragma unroll
    for (int t = 0; t < NT; t++)
#pragma unroll
        for (int j = 0; j < CJ; j++) acc[t][j] = 0.0f;

    for (int k4 = 0; k4 < K4; ++k4) {
        float4 xv[NT], wv[CJ];
#pragma unroll
        for (int t = 0; t < NT; ++t)
            xv[t] = *(const float4*)&sX[(rl + RT * t) * KP + k4 * 4];
#pragma unroll
        for (int j = 0; j < CJ; ++j)
            wv[j] = *(const float4*)&sW[(ob + NCT * j) * KP + k4 * 4];
#pragma unroll
        for (int t = 0; t < NT; ++t)
#pragma unroll
            for (int j = 0; j < CJ; ++j) {
                acc[t][j] = fmaf(xv[t].x, wv[j].x, acc[t][j]);
                acc[t][j] = fmaf(xv[t].y, wv[j].y, acc[t][j]);
                acc[t][j] = fmaf(xv[t].z, wv[j].z, acc[t][j]);
                acc[t][j] = fmaf(xv[t].w, wv[j].w, acc[t][j]);
            }
    }

    if (BLEND) {
#pragma unroll
        for (int t = 0; t < NT; ++t) {
            int r = rl + RT * t;
#pragma unroll
            for (int j = 0; j < CJ; ++j)
                acc[t][j] = (1.0f - beta) * sX[r * KP + ob + NCT * j] + beta * acc[t][j];
        }
    }

#pragma unroll
    for (int t = 0; t < NT; ++t) {
        const int r = rl + RT * t;
        const int n = nbase + r;
        const bool valid = n < N_NODES;
        if (PACKOUT) {
#pragma unroll
            for (int j = 0; j < CJ; ++j) {
                float p = __shfl_xor(acc[t][j], 1);
                if (valid && !(ob & 1))
                    outb[(size_t)n * (C / 2) + ((cbase + ob + NCT * j) >> 1)] =
                        packbf(acc[t][j], p);
            }
        } else if (valid) {
#pragma unroll
            for (int j = 0; j < CJ; ++j)
                outf[(size_t)n * C + cbase + ob + NCT * j] = acc[t][j];
        }
        if (H0OUT) {
#pragma unroll
            for (int j = 0; j < CJ; ++j) {
                float hv = sX[r * KP + ob + NCT * j];
                float hp = __shfl_xor(hv, 1);
                if (valid && !(ob & 1))
                    h0n[(size_t)n * (C / 2) + ((ob + NCT * j) >> 1)] = packbf(hv, hp);
            }
        }
    }

    if (STATS) {
#pragma unroll
        for (int j = 0; j < CJ; ++j) {
            float s = 0.0f, q = 0.0f;
#pragma unroll
            for (int t = 0; t < NT; ++t) { s += acc[t][j]; q += acc[t][j] * acc[t][j]; }
#pragma unroll
            for (int m = NCT; m < 64; m <<= 1) { s += __shfl_xor(s, m); q += __shfl_xor(q, m); }
            if ((tid & 63) < NCT) {
                atomicAdd(&osum[cbase + ob + NCT * j], s);
                atomicAdd(&osq[cbase + ob + NCT * j], q);
            }
        }
    }
}

// ---------------- SpMM v3: bf16 gather table ----------------

template <int C, bool LAYER, bool STATS>
__global__ __launch_bounds__(256) void spmm3(
    const uint2* __restrict__ tb, const uint2* __restrict__ h0n,
    const int* __restrict__ row_start, const int2* __restrict__ cw,
    const float* __restrict__ selfw, float4* __restrict__ outf,
    float* __restrict__ osum, float* __restrict__ osq) {
    constexpr int C4 = C / 4;
    __shared__ float ssum[STATS ? C : 1];
    __shared__ float ssq[STATS ? C : 1];
    const int tid = threadIdx.x;
    if (STATS) {
        if (tid < C) { ssum[tid] = 0.0f; ssq[tid] = 0.0f; }
        __syncthreads();
    }
    const int total = N_NODES * C4;
    for (int idx = blockIdx.x * 256 + tid; idx < total; idx += gridDim.x * 256) {
        const int n = idx / C4;
        const int c4 = idx - n * C4;
        const float sw = selfw[n];
        float4 acc = unpack4(tb[idx]);
        acc.x *= sw; acc.y *= sw; acc.z *= sw; acc.w *= sw;
        const int rs = row_start[n], re = row_start[n + 1];
        int j = rs;
        for (; j + 3 < re; j += 4) {
            int2 e0 = cw[j], e1 = cw[j + 1], e2 = cw[j + 2], e3 = cw[j + 3];
            uint2 p0 = tb[(size_t)e0.x * C4 + c4];
            uint2 p1 = tb[(size_t)e1.x * C4 + c4];
            uint2 p2 = tb[(size_t)e2.x * C4 + c4];
            uint2 p3 = tb[(size_t)e3.x * C4 + c4];
            float w0 = __int_as_float(e0.y), w1 = __int_as_float(e1.y);
            float w2 = __int_as_float(e2.y), w3 = __int_as_float(e3.y);
            float4 a0 = unpack4(p0), a1 = unpack4(p1), a2 = unpack4(p2), a3 = unpack4(p3);
            acc.x = fmaf(w0, a0.x, acc.x); acc.y = fmaf(w0, a0.y, acc.y);
            acc.z = fmaf(w0, a0.z, acc.z); acc.w = fmaf(w0, a0.w, acc.w);
            acc.x = fmaf(w1, a1.x, acc.x); acc.y = fmaf(w1, a1.y, acc.y);
            acc.z = fmaf(w1, a1.z, acc.z); acc.w = fmaf(w1, a1.w, acc.w);
            acc.x = fmaf(w2, a2.x, acc.x); acc.y = fmaf(w2, a2.y, acc.y);
            acc.z = fmaf(w2, a2.z, acc.z); acc.w = fmaf(w2, a2.w, acc.w);
            acc.x = fmaf(w3, a3.x, acc.x); acc.y = fmaf(w3, a3.y, acc.y);
            acc.z = fmaf(w3, a3.z, acc.z); acc.w = fmaf(w3, a3.w, acc.w);
        }
        for (; j < re; ++j) {
            int2 e0 = cw[j];
            uint2 p0 = tb[(size_t)e0.x * C4 + c4];
            float w0 = __int_as_float(e0.y);
            float4 a0 = unpack4(p0);
            acc.x = fmaf(w0, a0.x, acc.x); acc.y = fmaf(w0, a0.y, acc.y);
            acc.z = fmaf(w0, a0.z, acc.z); acc.w = fmaf(w0, a0.w, acc.w);
        }
        if (LAYER) {
            float4 h0 = unpack4(h0n[idx]);
            acc.x = 0.9f * acc.x + 0.1f * h0.x;
            acc.y = 0.9f * acc.y + 0.1f * h0.y;
            acc.z = 0.9f * acc.z + 0.1f * h0.z;
            acc.w = 0.9f * acc.w + 0.1f * h0.w;
        }
        outf[idx] = acc;
        if (STATS) {
            int c = c4 * 4;
            atomicAdd(&ssum[c + 0], acc.x); atomicAdd(&ssq[c + 0], acc.x * acc.x);
            atomicAdd(&ssum[c + 1], acc.y); atomicAdd(&ssq[c + 1], acc.y * acc.y);
            atomicAdd(&ssum[c + 2], acc.z); atomicAdd(&ssq[c + 2], acc.z * acc.z);
            atomicAdd(&ssum[c + 3], acc.w); atomicAdd(&ssq[c + 3], acc.w * acc.w);
        }
    }
    if (STATS) {
        __syncthreads();
        if (tid < C) {
            atomicAdd(&osum[tid], ssum[tid]);
            atomicAdd(&osq[tid], ssq[tid]);
        }
    }
}

// ---------------- launch ----------------

extern "C" void kernel_launch(void* const* d_in, const int* in_sizes, int n_in,
                              void* d_out, int out_size, void* d_ws, size_t ws_size,
                              hipStream_t stream) {
    const float* x  = (const float*)d_in[0];
    const int*   ei = (const int*)d_in[1];
    const float* W0 = (const float*)d_in[2];
    const float* W1 = (const float*)d_in[3];
    const float* W2 = (const float*)d_in[4];
    const float* W3 = (const float*)d_in[5];
    float* out = (float*)d_out;

    char* w = (char*)d_ws;
    auto alloc = [&](size_t bytes) {
        void* p = (void*)w;
        w += (bytes + 255) & ~(size_t)255;
        return p;
    };
    int*      cnt       = (int*)alloc(N_NODES * 4);
    int*      row_start = (int*)alloc((N_NODES + 1) * 4);
    int*      fillp     = (int*)alloc(N_NODES * 4);
    int2*     cw        = (int2*)alloc((size_t)N_EDGES * 8);
    float*    dinv      = (float*)alloc(N_NODES * 4);
    float*    selfw     = (float*)alloc(N_NODES * 4);
    float*    g0        = (float*)alloc((size_t)N_NODES * HID_CH * 4);
    float*    s         = (float*)alloc((size_t)N_NODES * HID_CH * 4);
    unsigned* tb        = (unsigned*)alloc((size_t)N_NODES * (HID_CH / 2) * 4);
    unsigned* h0n       = (unsigned*)alloc((size_t)N_NODES * (HID_CH / 2) * 4);
    float*    stats     = (float*)alloc(6 * HID_CH * 4);
    float*    mu0  = (float*)alloc(HID_CH * 4);
    float*    inv0 = (float*)alloc(HID_CH * 4);
    float*    mu1  = (float*)alloc(HID_CH * 4);
    float*    inv1 = (float*)alloc(HID_CH * 4);
    float*    mu2  = (float*)alloc(HID_CH * 4);
    float*    inv2 = (float*)alloc(HID_CH * 4);
    float* sums0 = stats,              * sq0 = stats + HID_CH;
    float* sums1 = stats + 2 * HID_CH, * sq1 = stats + 3 * HID_CH;
    float* sums2 = stats + 4 * HID_CH, * sq2 = stats + 5 * HID_CH;

    const int EB = (N_EDGES + 255) / 256;
    const int NB = (N_NODES + 255) / 256;
    const int G64 = (N_NODES + 63) / 64;       // 782 blocks of 64 rows

    hipMemsetAsync(cnt, 0, N_NODES * 4, stream);
    hipMemsetAsync(fillp, 0, N_NODES * 4, stream);
    hipMemsetAsync(stats, 0, 6 * HID_CH * 4, stream);

    count_kernel<<<EB, 256, 0, stream>>>(ei, cnt);
    norm_kernel<<<NB, 256, 0, stream>>>(cnt, dinv, selfw);
    scan_kernel<<<1, 256, 0, stream>>>(cnt, row_start);
    fill_kernel<<<EB, 256, 0, stream>>>(ei, row_start, fillp, dinv, cw);

    // layer 0: g0 = x @ W0^T (fp32) + stats0.  K=128 -> C-split 2 (LDS fit).
    gemm5<IN_CH, HID_CH, 16, 3, 4, 2, false, false, true, false, false>
        <<<G64 * 2, 256, 0, stream>>>(x, W0, g0, nullptr, nullptr, nullptr, nullptr,
                                      sums0, sq0, 0.0f);
    bn_fin<<<1, HID_CH, 0, stream>>>(sums0, sq0, mu0, inv0);

    // layer 1: tb = bf16(blend(hn0, hn0@W1^T, .5)); h0n = bf16(hn0)
    gemm5<HID_CH, HID_CH, 16, 6, 4, 1, true, true, false, true, true>
        <<<G64, 256, 0, stream>>>(g0, W1, nullptr, tb, h0n, mu0, inv0, nullptr, nullptr, 0.5f);
    spmm3<HID_CH, true, true><<<2048, 256, 0, stream>>>(
        (const uint2*)tb, (const uint2*)h0n, row_start, cw, selfw, (float4*)s, sums1, sq1);
    bn_fin<<<1, HID_CH, 0, stream>>>(sums1, sq1, mu1, inv1);

    // layer 2: tb = bf16(blend(hn1, hn1@W2^T, .25))
    gemm5<HID_CH, HID_CH, 16, 6, 4, 1, true, true, false, true, false>
        <<<G64, 256, 0, stream>>>(s, W2, nullptr, tb, nullptr, mu1, inv1, nullptr, nullptr, 0.25f);
    spmm3<HID_CH, true, true><<<2048, 256, 0, stream>>>(
        (const uint2*)tb, (const uint2*)h0n, row_start, cw, selfw, (float4*)s, sums2, sq2);
    bn_fin<<<1, HID_CH, 0, stream>>>(sums2, sq2, mu2, inv2);

    // final: tb = bf16(hn2 @ W3^T); out = spmm(tb)
    gemm5<HID_CH, OUT_CH, 8, 5, 2, 1, false, true, false, true, false>
        <<<G64, 256, 0, stream>>>(s, W3, nullptr, tb, nullptr, mu2, inv2, nullptr, nullptr, 0.0f);
    spmm3<OUT_CH, false, false><<<1954, 256, 0, stream>>>(
        (const uint2*)tb, nullptr, row_start, cw, selfw, (float4*)out, nullptr, nullptr);
}

// Round 7
// 624.465 us; speedup vs baseline: 1.7023x; 1.2535x over previous
//
#include <hip/hip_runtime.h>

#define N_NODES 50000
#define N_EDGES 800000
#define IN_CH 128
#define HID_CH 96
#define OUT_CH 40
#define EPS 1e-5f

// ---------------- bf16 pack/unpack ----------------

__device__ __forceinline__ unsigned packbf(float a, float b) {
    unsigned ua = __float_as_uint(a), ub = __float_as_uint(b);
    ua += 0x7fffu + ((ua >> 16) & 1u);           // RTNE
    ub += 0x7fffu + ((ub >> 16) & 1u);
    return (ua >> 16) | (ub & 0xffff0000u);
}

struct f8 { float4 lo, hi; };

__device__ __forceinline__ f8 unpack8(uint4 v) {
    f8 r;
    r.lo = make_float4(__uint_as_float(v.x << 16), __uint_as_float(v.x & 0xffff0000u),
                       __uint_as_float(v.y << 16), __uint_as_float(v.y & 0xffff0000u));
    r.hi = make_float4(__uint_as_float(v.z << 16), __uint_as_float(v.z & 0xffff0000u),
                       __uint_as_float(v.w << 16), __uint_as_float(v.w & 0xffff0000u));
    return r;
}

// ---------------- CSR build ----------------

__global__ void count_kernel(const int* __restrict__ ei, int* __restrict__ cnt) {
    int e = blockIdx.x * blockDim.x + threadIdx.x;
    if (e >= N_EDGES) return;
    int s = ei[e], d = ei[N_EDGES + e];
    if (s != d) atomicAdd(&cnt[d], 1);
}

__global__ void norm_kernel(const int* __restrict__ cnt, float* __restrict__ dinv,
                            float* __restrict__ selfw) {
    int n = blockIdx.x * blockDim.x + threadIdx.x;
    if (n >= N_NODES) return;
    float deg = (float)(cnt[n] + 1);
    dinv[n]  = rsqrtf(deg);
    selfw[n] = 1.0f / deg;
}

__global__ void scan_kernel(const int* __restrict__ cnt, int* __restrict__ row_start) {
    __shared__ int partial[256];
    const int T = 256;
    int tid = threadIdx.x;
    int seg = (N_NODES + T - 1) / T;
    int s0 = tid * seg;
    int s1 = s0 + seg; if (s1 > N_NODES) s1 = N_NODES;
    int sum = 0;
    for (int i = s0; i < s1; i++) sum += cnt[i];
    partial[tid] = sum;
    __syncthreads();
    if (tid == 0) {
        int acc = 0;
        for (int i = 0; i < T; i++) { int v = partial[i]; partial[i] = acc; acc += v; }
    }
    __syncthreads();
    int acc = partial[tid];
    for (int i = s0; i < s1; i++) { row_start[i] = acc; acc += cnt[i]; }
    if (tid == T - 1) row_start[N_NODES] = acc;
}

__global__ void fill_kernel(const int* __restrict__ ei, const int* __restrict__ row_start,
                            int* __restrict__ fillp, const float* __restrict__ dinv,
                            int2* __restrict__ cw) {
    int e = blockIdx.x * blockDim.x + threadIdx.x;
    if (e >= N_EDGES) return;
    int s = ei[e], d = ei[N_EDGES + e];
    if (s == d) return;
    int p = atomicAdd(&fillp[d], 1);
    int idx = row_start[d] + p;
    cw[idx] = make_int2(s, __float_as_int(dinv[s] * dinv[d]));
}

__global__ void bn_fin(const float* __restrict__ sums, const float* __restrict__ sq,
                       float* __restrict__ mu, float* __restrict__ inv) {
    int c = threadIdx.x;
    if (c >= HID_CH) return;
    float m = sums[c] * (1.0f / N_NODES);
    float v = sq[c] * (1.0f / N_NODES) - m * m;
    mu[c] = m; inv[c] = rsqrtf(v + EPS);
}

// ---------------- GEMM v5b: W AND X in LDS; reg-capped, unroll-limited ----------
// 256 threads: ob = tid & (NCT-1) channel-lane; rl = tid / NCT row-lane.
// __launch_bounds__(256,4) caps VGPR at ~128 (r6 spilled at 256 VGPR -> 0.5 GB scratch).

template <int K, int C, int NCT, int CJ, int NT, int CSPLIT,
          bool BLEND, bool NORMX, bool STATS, bool PACKOUT, bool H0OUT>
__global__ __launch_bounds__(256, 4) void gemm5(
    const float* __restrict__ X, const float* __restrict__ W,
    float* __restrict__ outf, unsigned* __restrict__ outb, unsigned* __restrict__ h0n,
    const float* __restrict__ muin, const float* __restrict__ invin,
    float* __restrict__ osum, float* __restrict__ osq, float beta) {
    constexpr int K4 = K / 4;
    constexpr int KP = K + 4;                 // LDS row stride (floats)
    constexpr int CG = C / CSPLIT;            // channels per block
    constexpr int RT = 256 / NCT;             // row-threads
    constexpr int RPB = RT * NT;              // rows per block
    __shared__ float sW[CG * KP];
    __shared__ float sX[RPB * KP];
    const int tid = threadIdx.x;
    const int ob = tid & (NCT - 1);
    const int rl = tid / NCT;
    const int grp = (CSPLIT > 1) ? ((int)blockIdx.x % CSPLIT) : 0;
    const int nb  = (CSPLIT > 1) ? ((int)blockIdx.x / CSPLIT) : (int)blockIdx.x;
    const int cbase = grp * CG;
    const int nbase = nb * RPB;
    const float4* X4 = (const float4*)X;
    const float4* W4 = (const float4*)W;

    // stage W tile
    for (int i = tid; i < CG * K4; i += 256) {
        int o = i / K4, k4 = i - o * K4;
        *(float4*)&sW[o * KP + k4 * 4] = W4[(size_t)(cbase + o) * K4 + k4];
    }
    // stage X tile (normalized+ReLU if NORMX)
    for (int i = tid; i < RPB * K4; i += 256) {
        int r = i / K4, k4 = i - r * K4;
        int n = nbase + r;
        float4 v = make_float4(0.f, 0.f, 0.f, 0.f);
        if (n < N_NODES) v = X4[(size_t)n * K4 + k4];
        if (NORMX) {
            float4 m  = *(const float4*)&muin[k4 * 4];
            float4 iv = *(const float4*)&invin[k4 * 4];
            v.x = fmaxf((v.x - m.x) * iv.x, 0.0f);
            v.y = fmaxf((v.y - m.y) * iv.y, 0.0f);
            v.z = fmaxf((v.z - m.z) * iv.z, 0.0f);
            v.w = fmaxf((v.w - m.w) * iv.w, 0.0f);
        }
        *(float4*)&sX[r * KP + k4 * 4] = v;
    }
    __syncthreads();

    float acc[NT][CJ];
#pragma unroll
    for (int t = 0; t < NT; t++)
#pragma unroll
        for (int j = 0; j < CJ; j++) acc[t][j] = 0.0f;

#pragma unroll 2
    for (int k4 = 0; k4 < K4; ++k4) {
        float4 xv[NT], wv[CJ];
#pragma unroll
        for (int t = 0; t < NT; ++t)
            xv[t] = *(const float4*)&sX[(rl + RT * t) * KP + k4 * 4];
#pragma unroll
        for (int j = 0; j < CJ; ++j)
            wv[j] = *(const float4*)&sW[(ob + NCT * j) * KP + k4 * 4];
#pragma unroll
        for (int t = 0; t < NT; ++t)
#pragma unroll
            for (int j = 0; j < CJ; ++j) {
                acc[t][j] = fmaf(xv[t].x, wv[j].x, acc[t][j]);
                acc[t][j] = fmaf(xv[t].y, wv[j].y, acc[t][j]);
                acc[t][j] = fmaf(xv[t].z, wv[j].z, acc[t][j]);
                acc[t][j] = fmaf(xv[t].w, wv[j].w, acc[t][j]);
            }
    }

    if (BLEND) {
#pragma unroll
        for (int t = 0; t < NT; ++t) {
            int r = rl + RT * t;
#pragma unroll
            for (int j = 0; j < CJ; ++j)
                acc[t][j] = (1.0f - beta) * sX[r * KP + ob + NCT * j] + beta * acc[t][j];
        }
    }

#pragma unroll
    for (int t = 0; t < NT; ++t) {
        const int r = rl + RT * t;
        const int n = nbase + r;
        const bool valid = n < N_NODES;
        if (PACKOUT) {
#pragma unroll
            for (int j = 0; j < CJ; ++j) {
                float p = __shfl_xor(acc[t][j], 1);
                if (valid && !(ob & 1))
                    outb[(size_t)n * (C / 2) + ((cbase + ob + NCT * j) >> 1)] =
                        packbf(acc[t][j], p);
            }
        } else if (valid) {
#pragma unroll
            for (int j = 0; j < CJ; ++j)
                outf[(size_t)n * C + cbase + ob + NCT * j] = acc[t][j];
        }
        if (H0OUT) {
#pragma unroll
            for (int j = 0; j < CJ; ++j) {
                float hv = sX[r * KP + ob + NCT * j];
                float hp = __shfl_xor(hv, 1);
                if (valid && !(ob & 1))
                    h0n[(size_t)n * (C / 2) + ((ob + NCT * j) >> 1)] = packbf(hv, hp);
            }
        }
    }

    if (STATS) {
#pragma unroll
        for (int j = 0; j < CJ; ++j) {
            float s = 0.0f, q = 0.0f;
#pragma unroll
            for (int t = 0; t < NT; ++t) { s += acc[t][j]; q += acc[t][j] * acc[t][j]; }
#pragma unroll
            for (int m = NCT; m < 64; m <<= 1) { s += __shfl_xor(s, m); q += __shfl_xor(q, m); }
            if ((tid & 63) < NCT) {
                atomicAdd(&osum[cbase + ob + NCT * j], s);
                atomicAdd(&osq[cbase + ob + NCT * j], q);
            }
        }
    }
}

// ---------------- SpMM v4: bf16 gather table, uint4 (8 ch / thread) ----------------

template <int C, bool LAYER, bool STATS>
__global__ __launch_bounds__(256) void spmm4(
    const uint4* __restrict__ tb, const uint4* __restrict__ h0n,
    const int* __restrict__ row_start, const int2* __restrict__ cw,
    const float* __restrict__ selfw, float* __restrict__ outf,
    float* __restrict__ osum, float* __restrict__ osq) {
    constexpr int C8 = C / 8;
    __shared__ float ssum[STATS ? C : 1];
    __shared__ float ssq[STATS ? C : 1];
    const int tid = threadIdx.x;
    if (STATS) {
        if (tid < C) { ssum[tid] = 0.0f; ssq[tid] = 0.0f; }
        __syncthreads();
    }
    const int total = N_NODES * C8;
    for (int idx = blockIdx.x * 256 + tid; idx < total; idx += gridDim.x * 256) {
        const int n = idx / C8;
        const int c8 = idx - n * C8;
        const float sw = selfw[n];
        f8 acc = unpack8(tb[idx]);
        acc.lo.x *= sw; acc.lo.y *= sw; acc.lo.z *= sw; acc.lo.w *= sw;
        acc.hi.x *= sw; acc.hi.y *= sw; acc.hi.z *= sw; acc.hi.w *= sw;
        const int rs = row_start[n], re = row_start[n + 1];
        int j = rs;
        for (; j + 3 < re; j += 4) {
            int2 e0 = cw[j], e1 = cw[j + 1], e2 = cw[j + 2], e3 = cw[j + 3];
            uint4 p0 = tb[(size_t)e0.x * C8 + c8];
            uint4 p1 = tb[(size_t)e1.x * C8 + c8];
            uint4 p2 = tb[(size_t)e2.x * C8 + c8];
            uint4 p3 = tb[(size_t)e3.x * C8 + c8];
            float w0 = __int_as_float(e0.y), w1 = __int_as_float(e1.y);
            float w2 = __int_as_float(e2.y), w3 = __int_as_float(e3.y);
            f8 a0 = unpack8(p0), a1 = unpack8(p1), a2 = unpack8(p2), a3 = unpack8(p3);
            acc.lo.x = fmaf(w0, a0.lo.x, acc.lo.x); acc.lo.y = fmaf(w0, a0.lo.y, acc.lo.y);
            acc.lo.z = fmaf(w0, a0.lo.z, acc.lo.z); acc.lo.w = fmaf(w0, a0.lo.w, acc.lo.w);
            acc.hi.x = fmaf(w0, a0.hi.x, acc.hi.x); acc.hi.y = fmaf(w0, a0.hi.y, acc.hi.y);
            acc.hi.z = fmaf(w0, a0.hi.z, acc.hi.z); acc.hi.w = fmaf(w0, a0.hi.w, acc.hi.w);
            acc.lo.x = fmaf(w1, a1.lo.x, acc.lo.x); acc.lo.y = fmaf(w1, a1.lo.y, acc.lo.y);
            acc.lo.z = fmaf(w1, a1.lo.z, acc.lo.z); acc.lo.w = fmaf(w1, a1.lo.w, acc.lo.w);
            acc.hi.x = fmaf(w1, a1.hi.x, acc.hi.x); acc.hi.y = fmaf(w1, a1.hi.y, acc.hi.y);
            acc.hi.z = fmaf(w1, a1.hi.z, acc.hi.z); acc.hi.w = fmaf(w1, a1.hi.w, acc.hi.w);
            acc.lo.x = fmaf(w2, a2.lo.x, acc.lo.x); acc.lo.y = fmaf(w2, a2.lo.y, acc.lo.y);
            acc.lo.z = fmaf(w2, a2.lo.z, acc.lo.z); acc.lo.w = fmaf(w2, a2.lo.w, acc.lo.w);
            acc.hi.x = fmaf(w2, a2.hi.x, acc.hi.x); acc.hi.y = fmaf(w2, a2.hi.y, acc.hi.y);
            acc.hi.z = fmaf(w2, a2.hi.z, acc.hi.z); acc.hi.w = fmaf(w2, a2.hi.w, acc.hi.w);
            acc.lo.x = fmaf(w3, a3.lo.x, acc.lo.x); acc.lo.y = fmaf(w3, a3.lo.y, acc.lo.y);
            acc.lo.z = fmaf(w3, a3.lo.z, acc.lo.z); acc.lo.w = fmaf(w3, a3.lo.w, acc.lo.w);
            acc.hi.x = fmaf(w3, a3.hi.x, acc.hi.x); acc.hi.y = fmaf(w3, a3.hi.y, acc.hi.y);
            acc.hi.z = fmaf(w3, a3.hi.z, acc.hi.z); acc.hi.w = fmaf(w3, a3.hi.w, acc.hi.w);
        }
        for (; j < re; ++j) {
            int2 e0 = cw[j];
            uint4 p0 = tb[(size_t)e0.x * C8 + c8];
            float w0 = __int_as_float(e0.y);
            f8 a0 = unpack8(p0);
            acc.lo.x = fmaf(w0, a0.lo.x, acc.lo.x); acc.lo.y = fmaf(w0, a0.lo.y, acc.lo.y);
            acc.lo.z = fmaf(w0, a0.lo.z, acc.lo.z); acc.lo.w = fmaf(w0, a0.lo.w, acc.lo.w);
            acc.hi.x = fmaf(w0, a0.hi.x, acc.hi.x); acc.hi.y = fmaf(w0, a0.hi.y, acc.hi.y);
            acc.hi.z = fmaf(w0, a0.hi.z, acc.hi.z); acc.hi.w = fmaf(w0, a0.hi.w, acc.hi.w);
        }
        if (LAYER) {
            f8 h0 = unpack8(h0n[idx]);
            acc.lo.x = 0.9f * acc.lo.x + 0.1f * h0.lo.x;
            acc.lo.y = 0.9f * acc.lo.y + 0.1f * h0.lo.y;
            acc.lo.z = 0.9f * acc.lo.z + 0.1f * h0.lo.z;
            acc.lo.w = 0.9f * acc.lo.w + 0.1f * h0.lo.w;
            acc.hi.x = 0.9f * acc.hi.x + 0.1f * h0.hi.x;
            acc.hi.y = 0.9f * acc.hi.y + 0.1f * h0.hi.y;
            acc.hi.z = 0.9f * acc.hi.z + 0.1f * h0.hi.z;
            acc.hi.w = 0.9f * acc.hi.w + 0.1f * h0.hi.w;
        }
        float* op = outf + (size_t)n * C + c8 * 8;
        *(float4*)op = acc.lo;
        *(float4*)(op + 4) = acc.hi;
        if (STATS) {
            int c = c8 * 8;
            atomicAdd(&ssum[c + 0], acc.lo.x); atomicAdd(&ssq[c + 0], acc.lo.x * acc.lo.x);
            atomicAdd(&ssum[c + 1], acc.lo.y); atomicAdd(&ssq[c + 1], acc.lo.y * acc.lo.y);
            atomicAdd(&ssum[c + 2], acc.lo.z); atomicAdd(&ssq[c + 2], acc.lo.z * acc.lo.z);
            atomicAdd(&ssum[c + 3], acc.lo.w); atomicAdd(&ssq[c + 3], acc.lo.w * acc.lo.w);
            atomicAdd(&ssum[c + 4], acc.hi.x); atomicAdd(&ssq[c + 4], acc.hi.x * acc.hi.x);
            atomicAdd(&ssum[c + 5], acc.hi.y); atomicAdd(&ssq[c + 5], acc.hi.y * acc.hi.y);
            atomicAdd(&ssum[c + 6], acc.hi.z); atomicAdd(&ssq[c + 6], acc.hi.z * acc.hi.z);
            atomicAdd(&ssum[c + 7], acc.hi.w); atomicAdd(&ssq[c + 7], acc.hi.w * acc.hi.w);
        }
    }
    if (STATS) {
        __syncthreads();
        if (tid < C) {
            atomicAdd(&osum[tid], ssum[tid]);
            atomicAdd(&osq[tid], ssq[tid]);
        }
    }
}

// ---------------- launch ----------------

extern "C" void kernel_launch(void* const* d_in, const int* in_sizes, int n_in,
                              void* d_out, int out_size, void* d_ws, size_t ws_size,
                              hipStream_t stream) {
    const float* x  = (const float*)d_in[0];
    const int*   ei = (const int*)d_in[1];
    const float* W0 = (const float*)d_in[2];
    const float* W1 = (const float*)d_in[3];
    const float* W2 = (const float*)d_in[4];
    const float* W3 = (const float*)d_in[5];
    float* out = (float*)d_out;

    char* w = (char*)d_ws;
    auto alloc = [&](size_t bytes) {
        void* p = (void*)w;
        w += (bytes + 255) & ~(size_t)255;
        return p;
    };
    int*      cnt       = (int*)alloc(N_NODES * 4);
    int*      row_start = (int*)alloc((N_NODES + 1) * 4);
    int*      fillp     = (int*)alloc(N_NODES * 4);
    int2*     cw        = (int2*)alloc((size_t)N_EDGES * 8);
    float*    dinv      = (float*)alloc(N_NODES * 4);
    float*    selfw     = (float*)alloc(N_NODES * 4);
    float*    g0        = (float*)alloc((size_t)N_NODES * HID_CH * 4);
    float*    s         = (float*)alloc((size_t)N_NODES * HID_CH * 4);
    unsigned* tb        = (unsigned*)alloc((size_t)N_NODES * (HID_CH / 2) * 4);
    unsigned* h0n       = (unsigned*)alloc((size_t)N_NODES * (HID_CH / 2) * 4);
    float*    stats     = (float*)alloc(6 * HID_CH * 4);
    float*    mu0  = (float*)alloc(HID_CH * 4);
    float*    inv0 = (float*)alloc(HID_CH * 4);
    float*    mu1  = (float*)alloc(HID_CH * 4);
    float*    inv1 = (float*)alloc(HID_CH * 4);
    float*    mu2  = (float*)alloc(HID_CH * 4);
    float*    inv2 = (float*)alloc(HID_CH * 4);
    float* sums0 = stats,              * sq0 = stats + HID_CH;
    float* sums1 = stats + 2 * HID_CH, * sq1 = stats + 3 * HID_CH;
    float* sums2 = stats + 4 * HID_CH, * sq2 = stats + 5 * HID_CH;

    const int EB = (N_EDGES + 255) / 256;
    const int NB = (N_NODES + 255) / 256;
    const int G64 = (N_NODES + 63) / 64;       // 782 blocks of 64 rows

    hipMemsetAsync(cnt, 0, N_NODES * 4, stream);
    hipMemsetAsync(fillp, 0, N_NODES * 4, stream);
    hipMemsetAsync(stats, 0, 6 * HID_CH * 4, stream);

    count_kernel<<<EB, 256, 0, stream>>>(ei, cnt);
    norm_kernel<<<NB, 256, 0, stream>>>(cnt, dinv, selfw);
    scan_kernel<<<1, 256, 0, stream>>>(cnt, row_start);
    fill_kernel<<<EB, 256, 0, stream>>>(ei, row_start, fillp, dinv, cw);

    // layer 0: g0 = x @ W0^T (fp32) + stats0.  K=128 -> C-split 2 (LDS fit).
    gemm5<IN_CH, HID_CH, 16, 3, 4, 2, false, false, true, false, false>
        <<<G64 * 2, 256, 0, stream>>>(x, W0, g0, nullptr, nullptr, nullptr, nullptr,
                                      sums0, sq0, 0.0f);
    bn_fin<<<1, HID_CH, 0, stream>>>(sums0, sq0, mu0, inv0);

    // layer 1: tb = bf16(blend(hn0, hn0@W1^T, .5)); h0n = bf16(hn0)
    gemm5<HID_CH, HID_CH, 16, 6, 4, 1, true, true, false, true, true>
        <<<G64, 256, 0, stream>>>(g0, W1, nullptr, tb, h0n, mu0, inv0, nullptr, nullptr, 0.5f);
    spmm4<HID_CH, true, true><<<2344, 256, 0, stream>>>(
        (const uint4*)tb, (const uint4*)h0n, row_start, cw, selfw, s, sums1, sq1);
    bn_fin<<<1, HID_CH, 0, stream>>>(sums1, sq1, mu1, inv1);

    // layer 2: tb = bf16(blend(hn1, hn1@W2^T, .25))
    gemm5<HID_CH, HID_CH, 16, 6, 4, 1, true, true, false, true, false>
        <<<G64, 256, 0, stream>>>(s, W2, nullptr, tb, nullptr, mu1, inv1, nullptr, nullptr, 0.25f);
    spmm4<HID_CH, true, true><<<2344, 256, 0, stream>>>(
        (const uint4*)tb, (const uint4*)h0n, row_start, cw, selfw, s, sums2, sq2);
    bn_fin<<<1, HID_CH, 0, stream>>>(sums2, sq2, mu2, inv2);

    // final: tb = bf16(hn2 @ W3^T); out = spmm(tb)
    gemm5<HID_CH, OUT_CH, 8, 5, 2, 1, false, true, false, true, false>
        <<<G64, 256, 0, stream>>>(s, W3, nullptr, tb, nullptr, mu2, inv2, nullptr, nullptr, 0.0f);
    spmm4<OUT_CH, false, false><<<977, 256, 0, stream>>>(
        (const uint4*)tb, nullptr, row_start, cw, selfw, out, nullptr, nullptr);
}